// Round 15
// baseline (96.364 us; speedup 1.0000x reference)
//
#include <hip/hip_runtime.h>

#define NHEADS 8
#define NB 512
#define NN 1000
#define DD 128
#define HH 128
#define SDIM 384              // D*CAT
#define NSPLIT 4              // blocks per batch: 2048 blocks = EXACTLY 8/CU
#define NSLOT (NSPLIT * 4)    // one partial slot per wave (16)

// DPP helper: x += lane-permuted x. Pure VALU, no DS pipe.
template <int CTRL>
__device__ __forceinline__ float dpp_add(float x) {
    int y = __builtin_amdgcn_update_dpp(0, __float_as_int(x), CTRL, 0xf, 0xf, true);
    return x + __int_as_float(y);
}
#define DPP_QUAD_XOR1 0xB1   // quad_perm(1,0,3,2)
#define DPP_QUAD_XOR2 0x4E   // quad_perm(2,3,0,1)
#define DPP_HALF_MIRR 0x141  // mirror within 8
#define DPP_ROW_MIRR  0x140  // mirror within 16

// ---------------- kernel 0: per-batch qw precompute (coalesced) -------------
__global__ __launch_bounds__(256) void qw_kernel(
    const float* __restrict__ state_t,   // [B][384]
    const float* __restrict__ Wq,        // [128][384]
    const float* __restrict__ Wk,        // [128][128]
    float* __restrict__ qw)              // [B][8][128]
{
    const int b = blockIdx.x;
    const int t = threadIdx.x;
    const int lane = t & 63;
    const int w = t >> 6;

    __shared__ float s_q[HH];

    float st[6];
    #pragma unroll
    for (int j = 0; j < 6; ++j) st[j] = state_t[(size_t)b * SDIM + j * 64 + lane];

    for (int it = 0; it < 16; ++it) {
        const int r0 = w * 32 + it * 2;
        const float* w0 = Wq + (size_t)r0 * SDIM;
        const float* w1 = w0 + SDIM;
        float p0 = 0.f, p1 = 0.f;
        #pragma unroll
        for (int j = 0; j < 6; ++j) {
            p0 = fmaf(w0[j * 64 + lane], st[j], p0);
            p1 = fmaf(w1[j * 64 + lane], st[j], p1);
        }
        #pragma unroll
        for (int off = 32; off >= 1; off >>= 1) {
            p0 += __shfl_xor(p0, off, 64);
            p1 += __shfl_xor(p1, off, 64);
        }
        if (lane == 0) { s_q[r0] = p0; s_q[r0 + 1] = p1; }
    }
    __syncthreads();

    {
        const int d  = t & 127;
        const int h0 = (t >> 7) * 4;
        const float sc = 0.0625f * 1.4426950408889634f;  // (1/hd) * log2(e)
        for (int hh = 0; hh < 4; ++hh) {
            const int h = h0 + hh;
            float a = 0.f;
            #pragma unroll
            for (int j = 0; j < 16; ++j)
                a = fmaf(s_q[h * 16 + j], Wk[(size_t)(h * 16 + j) * DD + d], a);
            qw[(size_t)b * NHEADS * DD + h * DD + d] = a * sc;
        }
    }
}

// Wave-uniform mask for row k (runtime index): SALU readlane from mv.
#define MSK(kidx) (__builtin_amdgcn_readlane(mv, (kidx)))

// Load ctx row `idx` into buffer P if unmasked. idx must be < cnt.
#define CLD(P, idx)                                                           \
    {                                                                         \
        if (MSK(idx) == 0) {                                                  \
            const float* _np = cp + (size_t)(idx) * DD;                       \
            P##a = *reinterpret_cast<const float4*>(_np);                     \
            P##b = *reinterpret_cast<const float4*>(_np + 4);                 \
        }                                                                     \
    }

// Clamped variant for tail loads (row may not exist for cnt==62 waves).
#define CLDC(P, idx)                                                          \
    {                                                                         \
        const int _ci = (idx) < cnt ? (idx) : cnt - 1;                        \
        CLD(P, _ci)                                                           \
    }

// Process row `idx` held in buffer P; whole body skipped for masked rows.
#define BODY(P, idx)                                                          \
    {                                                                         \
        if (MSK(idx) == 0) {                                                  \
            const float4 C0 = P##a, C1 = P##b;                                \
            float sa = C0.x * qa0.x, sb = C0.x * qb0.x;                       \
            sa = fmaf(C0.y, qa0.y, sa); sb = fmaf(C0.y, qb0.y, sb);           \
            sa = fmaf(C0.z, qa0.z, sa); sb = fmaf(C0.z, qb0.z, sb);           \
            sa = fmaf(C0.w, qa0.w, sa); sb = fmaf(C0.w, qb0.w, sb);           \
            sa = fmaf(C1.x, qa1.x, sa); sb = fmaf(C1.x, qb1.x, sb);           \
            sa = fmaf(C1.y, qa1.y, sa); sb = fmaf(C1.y, qb1.y, sb);           \
            sa = fmaf(C1.z, qa1.z, sa); sb = fmaf(C1.z, qb1.z, sb);           \
            sa = fmaf(C1.w, qa1.w, sa); sb = fmaf(C1.w, qb1.w, sb);           \
            sa = dpp_add<DPP_QUAD_XOR1>(sa); sb = dpp_add<DPP_QUAD_XOR1>(sb); \
            sa = dpp_add<DPP_QUAD_XOR2>(sa); sb = dpp_add<DPP_QUAD_XOR2>(sb); \
            sa = dpp_add<DPP_HALF_MIRR>(sa); sb = dpp_add<DPP_HALF_MIRR>(sb); \
            sa = dpp_add<DPP_ROW_MIRR>(sa);  sb = dpp_add<DPP_ROW_MIRR>(sb);  \
            const float pa = exp2f(sa);                                       \
            const float pb = exp2f(sb);                                       \
            den0 += pa; den1 += pb;                                           \
            A0.x = fmaf(pa, C0.x, A0.x); B0.x = fmaf(pb, C0.x, B0.x);         \
            A0.y = fmaf(pa, C0.y, A0.y); B0.y = fmaf(pb, C0.y, B0.y);         \
            A0.z = fmaf(pa, C0.z, A0.z); B0.z = fmaf(pb, C0.z, B0.z);         \
            A0.w = fmaf(pa, C0.w, A0.w); B0.w = fmaf(pb, C0.w, B0.w);         \
            A1.x = fmaf(pa, C1.x, A1.x); B1.x = fmaf(pb, C1.x, B1.x);         \
            A1.y = fmaf(pa, C1.y, A1.y); B1.y = fmaf(pb, C1.y, B1.y);         \
            A1.z = fmaf(pa, C1.z, A1.z); B1.z = fmaf(pb, C1.z, B1.z);         \
            A1.w = fmaf(pa, C1.w, A1.w); B1.w = fmaf(pb, C1.w, B1.w);         \
        }                                                                     \
    }

// ---------------- kernel 1: partial score+softmax-accumulate ----------------
// Block = (split s, batch b), 256 threads = 4 waves; waves take 63/63/62/62
// contiguous rows. Wave = 4 groups of 16 lanes; group g = head pair (2g,2g+1);
// lane j owns floats [j*8, j*8+8).
// ROLLED main loop (#pragma unroll 1): body = 6 rows ~ 3KB code (fits I$ vs
// ~27KB fully unrolled), 6 rotating buffers (prefetch distance 6 rows = ~3
// ACTIVE bodies at 50% mask -> pipeline survives masked-row runs).
// Masked rows skip body AND loads. Grid = 2048 = exactly 8 blocks/CU.
// NO fence, NO atomics (R8: device fences ~0.7ms chip-wide).
__global__ __launch_bounds__(256, 4) void attn_partial_kernel(
    const float* __restrict__ context,   // [B][N][128]
    const int*   __restrict__ mask,      // [B][N]
    const float* __restrict__ qw,        // [B][8][128] (pre-scaled)
    float* __restrict__ part_acc,        // [B][NSLOT][8][128]
    float* __restrict__ part_den)        // [B][NSLOT][8]
{
    const int s = blockIdx.x;
    const int b = blockIdx.y;
    const int w = threadIdx.x >> 6;
    const int lane = threadIdx.x & 63;
    const int g = lane >> 4;     // head pair
    const int j = lane & 15;     // d-slice

    const int cnt  = (w < 2) ? 63 : 62;
    const int row0 = s * 250 + ((w < 2) ? w * 63 : 126 + (w - 2) * 62);
    const float* cp = context + ((size_t)b * NN + row0) * DD + j * 8;
    const int*   mp = mask + (size_t)b * NN + row0;

    // one load: lane i holds mask of row i (clamped; cnt <= 63 < 64)
    const int mv = mp[lane < cnt ? lane : cnt - 1];

    // qw slices for heads 2g, 2g+1 (16 regs)
    const float* qwb = qw + (size_t)b * NHEADS * DD + j * 8;
    const float4 qa0 = *reinterpret_cast<const float4*>(qwb + (2 * g) * DD);
    const float4 qa1 = *reinterpret_cast<const float4*>(qwb + (2 * g) * DD + 4);
    const float4 qb0 = *reinterpret_cast<const float4*>(qwb + (2 * g + 1) * DD);
    const float4 qb1 = *reinterpret_cast<const float4*>(qwb + (2 * g + 1) * DD + 4);

    float4 A0 = make_float4(0.f, 0.f, 0.f, 0.f), A1 = A0;  // acc head 2g
    float4 B0 = A0, B1 = A0;                                // acc head 2g+1
    float den0 = 0.f, den1 = 0.f;

    // 6 rotating single-row buffers (named locals; ~48 VGPR)
    float4 b0a, b0b, b1a, b1b, b2a, b2b, b3a, b3b, b4a, b4b, b5a, b5b;
    CLD(b0, 0) CLD(b1, 1) CLD(b2, 2) CLD(b3, 3) CLD(b4, 4) CLD(b5, 5)

    // rows 0..53: rolled, 9 iterations x 6 bodies; prefetch +6 (max 59 < cnt)
    #pragma unroll 1
    for (int k = 0; k < 54; k += 6) {
        BODY(b0, k)     CLD(b0, k + 6)
        BODY(b1, k + 1) CLD(b1, k + 7)
        BODY(b2, k + 2) CLD(b2, k + 8)
        BODY(b3, k + 3) CLD(b3, k + 9)
        BODY(b4, k + 4) CLD(b4, k + 10)
        BODY(b5, k + 5) CLD(b5, k + 11)
    }
    // tail: rows 54..61 (+62 for cnt==63 waves); tail loads clamped
    BODY(b0, 54) CLDC(b0, 60)
    BODY(b1, 55) CLDC(b1, 61)
    BODY(b2, 56) CLDC(b2, 62)
    BODY(b3, 57)
    BODY(b4, 58)
    BODY(b5, 59)
    BODY(b0, 60)
    BODY(b1, 61)
    if (cnt > 62) BODY(b2, 62)

    // ---- write this wave's partial slot (no LDS, no barrier) ----
    const int slot = s * 4 + w;
    float* pa_ = part_acc + (((size_t)b * NSLOT + slot) * NHEADS) * DD + j * 8;
    *reinterpret_cast<float4*>(pa_ + (2 * g) * DD)         = A0;
    *reinterpret_cast<float4*>(pa_ + (2 * g) * DD + 4)     = A1;
    *reinterpret_cast<float4*>(pa_ + (2 * g + 1) * DD)     = B0;
    *reinterpret_cast<float4*>(pa_ + (2 * g + 1) * DD + 4) = B1;
    if (j == 0) {
        float* pd = part_den + ((size_t)b * NSLOT + slot) * NHEADS;
        pd[2 * g]     = den0;
        pd[2 * g + 1] = den1;
    }
}

// ---------------- kernel 2: combine slots + Wv/Wfc projections --------------
__global__ __launch_bounds__(128) void attn_combine_kernel(
    const float* __restrict__ part_acc,  // [B][NSLOT][8][128]
    const float* __restrict__ part_den,  // [B][NSLOT][8]
    const float* __restrict__ Wv,        // [128][128]
    const float* __restrict__ Wfc,       // [128][128]
    float* __restrict__ out)             // [B][128]
{
    const int b = blockIdx.x;
    const int t = threadIdx.x;   // 128 threads

    __shared__ float s_dn[NHEADS];
    __shared__ float s_ca[NHEADS][132];
    __shared__ float s_o2[HH];

    if (t < NHEADS) {
        float dn = 0.f;
        #pragma unroll
        for (int sp = 0; sp < NSLOT; ++sp)
            dn += part_den[((size_t)b * NSLOT + sp) * NHEADS + t];
        s_dn[t] = dn;
    }
    __syncthreads();

    {
        const int d = t;
        #pragma unroll
        for (int h = 0; h < NHEADS; ++h) {
            float a = 0.f;
            #pragma unroll
            for (int sp = 0; sp < NSLOT; ++sp)
                a += part_acc[(((size_t)b * NSLOT + sp) * NHEADS + h) * DD + d];
            s_ca[h][d] = a / s_dn[h];
        }
    }
    __syncthreads();

    {
        const int h = t >> 4;
        const float* wvr = Wv + (size_t)t * DD;
        float a = 0.f;
        #pragma unroll 4
        for (int d = 0; d < DD; ++d) a = fmaf(s_ca[h][d], wvr[d], a);
        s_o2[t] = a;
    }
    __syncthreads();

    {
        const float* wfc = Wfc + (size_t)t * DD;
        float a = 0.f;
        #pragma unroll 4
        for (int k = 0; k < DD; ++k) a = fmaf(s_o2[k], wfc[k], a);
        out[(size_t)b * HH + t] = a;
    }
}

extern "C" void kernel_launch(void* const* d_in, const int* in_sizes, int n_in,
                              void* d_out, int out_size, void* d_ws, size_t ws_size,
                              hipStream_t stream) {
    const float* state_t = (const float*)d_in[0];
    const float* context = (const float*)d_in[1];
    const int*   mask    = (const int*)d_in[2];
    const float* Wq      = (const float*)d_in[3];
    const float* Wk      = (const float*)d_in[4];
    const float* Wv      = (const float*)d_in[5];
    const float* Wfc     = (const float*)d_in[6];
    float* out = (float*)d_out;

    float* qw       = (float*)d_ws;                                  // 2 MB
    float* part_acc = qw + (size_t)NB * NHEADS * DD;                 // 33.5 MB
    float* part_den = part_acc + (size_t)NB * NSLOT * NHEADS * DD;   // 0.26 MB

    qw_kernel<<<dim3(NB), dim3(256), 0, stream>>>(state_t, Wq, Wk, qw);
    attn_partial_kernel<<<dim3(NSPLIT, NB), dim3(256), 0, stream>>>(
        context, mask, qw, part_acc, part_den);
    attn_combine_kernel<<<dim3(NB), dim3(128), 0, stream>>>(
        part_acc, part_den, Wv, Wfc, out);
}